// Round 9
// baseline (1593.884 us; speedup 1.0000x reference)
//
#include <hip/hip_runtime.h>
#include <hip/hip_bf16.h>
#include <stdint.h>

typedef __attribute__((ext_vector_type(8))) short short8;
typedef __attribute__((ext_vector_type(4))) float floatx4;
typedef __attribute__((ext_vector_type(4))) unsigned int uintx4;
typedef __attribute__((ext_vector_type(4))) unsigned short ushort4v;

#define DEVI __device__ __forceinline__

// ---- problem sizes ----
constexpr int B_ = 256, T_ = 512, D_ = 128, H_ = 512, C_ = 10;
constexpr int KTOT = H_ + D_;       // 640: k = [h(512) ; x(128)]
constexpr int RG = 16;              // batch rows per group
constexpr int NBG = 16;             // batch groups
constexpr int NCG = 16;             // column groups
constexpr int HCW = 32;             // h-cols per WG
constexpr int ROWB = RG * KTOT * 2; // 20480 B per LDS buffer

// ---- workspace layout (bytes) ----
constexpr size_t OFF_XB = 0;
constexpr size_t SZ_XB  = (size_t)B_ * T_ * D_ * 2;          // x in bf16
constexpr size_t OFF_WC = OFF_XB + SZ_XB;
constexpr size_t SZ_WC  = (size_t)4 * H_ * KTOT * 2;         // Wcomb[4*H][640] bf16
constexpr size_t OFF_HB = OFF_WC + SZ_WC;
constexpr size_t SZ_HB  = (size_t)2 * B_ * H_ * 2;           // h double buffer bf16
constexpr size_t OFF_FL = OFF_HB + SZ_HB;
constexpr size_t SZ_FL  = (size_t)NBG * NCG * 64;            // flags: 64B apart
constexpr size_t WS_NEED = OFF_FL + SZ_FL;

DEVI uint16_t f2bf(float f) {
    uint32_t u = __builtin_bit_cast(uint32_t, f);
    u += 0x7FFFu + ((u >> 16) & 1u);
    return (uint16_t)(u >> 16);
}
DEVI float bf2f(uint16_t u) {
    return __builtin_bit_cast(float, (uint32_t)u << 16);
}
DEVI float sigf(float x)  { return 1.0f / (1.0f + __expf(-x)); }
DEVI float tanhf_(float x){ return 1.0f - 2.0f / (1.0f + __expf(2.0f * x)); }

// ---- prep: x fp32 -> bf16 ----
__global__ void k_cvt_x(const float* __restrict__ x, uint16_t* __restrict__ xb) {
    int i = (blockIdx.x * 256 + threadIdx.x) * 4;
    float4 v = *reinterpret_cast<const float4*>(x + i);
    ushort4v o;
    o.x = f2bf(v.x); o.y = f2bf(v.y); o.z = f2bf(v.z); o.w = f2bf(v.w);
    *reinterpret_cast<ushort4v*>(xb + i) = o;
}

// ---- prep: build combined transposed bf16 weights Wcomb[n'=g*512+n][k] ----
__global__ void k_build_w(const float* __restrict__ wgh, const float* __restrict__ wih,
                          const float* __restrict__ wfh, const float* __restrict__ woh,
                          const float* __restrict__ wgx, const float* __restrict__ wix,
                          const float* __restrict__ wfx, const float* __restrict__ wox,
                          uint16_t* __restrict__ wc) {
    int np = blockIdx.x;            // 0..2047
    int g = np >> 9, n = np & 511;
    const float* wh = (g == 0) ? wgh : (g == 1) ? wih : (g == 2) ? wfh : woh;
    const float* wx = (g == 0) ? wgx : (g == 1) ? wix : (g == 2) ? wfx : wox;
    for (int k = threadIdx.x; k < KTOT; k += 256) {
        float v = (k < H_) ? wh[(size_t)k * H_ + n] : wx[(size_t)(k - H_) * H_ + n];
        wc[(size_t)np * KTOT + k] = f2bf(v);
    }
}

// Opaque 16B weight load (kept resident in the unified VGPR/AGPR file)
#define WLOAD(dst, base, IMM) \
    asm volatile("global_load_dwordx4 %0, %1, off offset:" #IMM \
                 : "=v"(dst) : "v"(base))
#define WLOAD20(arr, base) \
    WLOAD(arr[0],  base, 0);    WLOAD(arr[1],  base, 64);   \
    WLOAD(arr[2],  base, 128);  WLOAD(arr[3],  base, 192);  \
    WLOAD(arr[4],  base, 256);  WLOAD(arr[5],  base, 320);  \
    WLOAD(arr[6],  base, 384);  WLOAD(arr[7],  base, 448);  \
    WLOAD(arr[8],  base, 512);  WLOAD(arr[9],  base, 576);  \
    WLOAD(arr[10], base, 640);  WLOAD(arr[11], base, 704);  \
    WLOAD(arr[12], base, 768);  WLOAD(arr[13], base, 832);  \
    WLOAD(arr[14], base, 896);  WLOAD(arr[15], base, 960);  \
    WLOAD(arr[16], base, 1024); WLOAD(arr[17], base, 1088); \
    WLOAD(arr[18], base, 1152); WLOAD(arr[19], base, 1216)

// device-coherent 16B load (h exchange)
#define HLOAD(dst, base, IMM) \
    asm volatile("global_load_dwordx4 %0, %1, off offset:" #IMM " sc0 sc1" \
                 : "=v"(dst) : "v"(base) : "memory")

// ---- main recurrent kernel ----
// WG = 16 batch rows x 32 h-cols, 4 waves (one gate per wave).
// Per step, wave w stages 5 K-slices into the double-buffered LDS A-tile:
//   x-slice (kstep 16+w, always ready) and h-slices w*4..w*4+3 (kstep ids),
//   the latter gated by 4 per-producer global flags polled in parallel.
// A per-wave LDS flag (release/acquire, epoch=t) publishes the staging; the
// MFMA loop starts after all 4 wave flags reach t and is branch-free.
// Producer side (validated round-2/8 semantics): h store (agent relaxed,
// sc1) -> vmcnt(0) drain -> barrier -> tid0 stores own cg flag (epoch t+1).
__global__ __launch_bounds__(256, 1) void k_lstm(
    const uint16_t* __restrict__ xb,   // [B][T][D] bf16
    const uint16_t* __restrict__ wc,   // [4H][KTOT] bf16
    const float* __restrict__ bgp, const float* __restrict__ bip,
    const float* __restrict__ bfp, const float* __restrict__ bop,
    uint16_t* hbuf,                    // [2][B][H] bf16
    int* flags)                        // [NBG][NCG] ints, 64B apart
{
    __shared__ __align__(16) char hx[2][ROWB];                    // 2 x 20 KB, XOR-swizzled
    __shared__ float pre[4][RG][HCW + 1];                         // stride 33
    __shared__ int waveflag[4];

    const int tid  = threadIdx.x;
    const int lane = tid & 63;
    const int w    = tid >> 6;          // wave id == gate id (g,i,f,o)
    const int bid  = blockIdx.x;
    // keep each batch-group's 16 WGs on one XCD (perf heuristic only)
    const int xcd = bid & 7, j = bid >> 3;
    const int bg = xcd * 2 + (j >> 4);
    const int cg = j & 15;
    const int b0  = bg * RG;
    const int hc0 = cg * HCW;

    // ---- load this wave's weight slice into registers (resident all run) ----
    short8 bfr0[20], bfr1[20];
    {
        const int lcol = lane & 15, kgrp = lane >> 4;
        const uint16_t* src0 = wc + (size_t)(w * H_ + hc0 + 0  + lcol) * KTOT + kgrp * 8;
        const uint16_t* src1 = wc + (size_t)(w * H_ + hc0 + 16 + lcol) * KTOT + kgrp * 8;
        WLOAD20(bfr0, src0);
        WLOAD20(bfr1, src1);
        asm volatile("s_waitcnt vmcnt(0)" ::: "memory");
    }

    // ---- elementwise thread mapping ----
    const int erow = tid >> 4;          // 0..15
    const int epr  = tid & 15;          // cols epr*2, epr*2+1
    const int hcg0 = hc0 + epr * 2;
    float bge[2], bie[2], bfe[2], boe[2], cst[2] = {0.f, 0.f};
    #pragma unroll
    for (int e = 0; e < 2; ++e) {
        bge[e] = bgp[hcg0 + e]; bie[e] = bip[hcg0 + e];
        bfe[e] = bfp[hcg0 + e]; boe[e] = bop[hcg0 + e];
    }

    // staging + A-fragment lane mapping (identical shapes)
    const int row = lane & 15;          // A row / staging row
    const int cb  = lane >> 4;          // 16B column block within a 32-col slice
    const int swz = (row & 7) << 4;

    int* fbase = flags + bg * NCG * 16;
    int* myflag = fbase + cg * 16;
    const int* pollp = fbase + (w * 4 + (lane & 3)) * 16;   // this wave's 4 producers

    if (tid < 4) waveflag[tid] = -1;
    __syncthreads();

    for (int t = 0; t < T_; ++t) {
        char* buf = hx[t & 1];

        // ---- stage x slice (kstep 16+w): no dependence on h ----
        const short8 xv = *reinterpret_cast<const short8*>(
            xb + ((size_t)(b0 + row) * T_ + t) * D_ + w * 32 + cb * 8);

        uintx4 v0, v1, v2, v3;
        if (t > 0) {
            // ---- poll own 4 producer flags in parallel (lanes via lane&3) ----
            int it = 0;
            for (;;) {
                int f = __hip_atomic_load(pollp, __ATOMIC_RELAXED, __HIP_MEMORY_SCOPE_AGENT);
                if (__all(f >= t)) break;
                if (++it > (1 << 22)) break;   // fail loud, not hang
            }
            asm volatile("" ::: "memory");
            // ---- load own 4 h slices (imm offsets from one base) ----
            const uint16_t* hbase = hbuf + (size_t)(t & 1) * B_ * H_
                                         + (size_t)(b0 + row) * H_ + w * 128 + cb * 8;
            HLOAD(v0, hbase, 0);
            HLOAD(v1, hbase, 64);
            HLOAD(v2, hbase, 128);
            HLOAD(v3, hbase, 192);
        }
        asm volatile("s_waitcnt vmcnt(0)" ::: "memory");

        // ---- LDS writes (swizzled) ----
        {   // x: kstep 16+w
            int byte = row * (KTOT * 2) + 1024 + w * 64 + cb * 16;
            *reinterpret_cast<short8*>(buf + (byte ^ swz)) = xv;
        }
        if (t > 0) {
            #pragma unroll
            for (int i = 0; i < 4; ++i) {
                uintx4 v = (i == 0) ? v0 : (i == 1) ? v1 : (i == 2) ? v2 : v3;
                int byte = row * (KTOT * 2) + (w * 4 + i) * 64 + cb * 16;
                *reinterpret_cast<uintx4*>(buf + (byte ^ swz)) = v;
            }
        } else {
            uintx4 z = {0u, 0u, 0u, 0u};
            #pragma unroll
            for (int i = 0; i < 4; ++i) {
                int byte = row * (KTOT * 2) + (w * 4 + i) * 64 + cb * 16;
                *reinterpret_cast<uintx4*>(buf + (byte ^ swz)) = z;
            }
        }
        // publish this wave's staging (release orders the ds_writes above)
        __hip_atomic_store(&waveflag[w], t, __ATOMIC_RELEASE, __HIP_MEMORY_SCOPE_WORKGROUP);

        // ---- wait for all 4 waves' staging ----
        {
            volatile int* wf = (volatile int*)waveflag;
            int it = 0;
            for (;;) {
                int f0 = wf[0], f1 = wf[1], f2 = wf[2], f3 = wf[3];
                if (f0 >= t && f1 >= t && f2 >= t && f3 >= t) break;
                if (++it > (1 << 25)) break;
            }
            asm volatile("" ::: "memory");
            __builtin_amdgcn_sched_barrier(0);
        }

        // ---- MFMA: branch-free, 20 ksteps (x first: 16..19, then h 0..15) ----
        floatx4 acc0 = {0.f, 0.f, 0.f, 0.f}, acc1 = {0.f, 0.f, 0.f, 0.f};
        #pragma unroll
        for (int i = 0; i < 20; ++i) {
            const int ks = (i < 4) ? (16 + i) : (i - 4);
            int byte = (row * (KTOT * 2) + ks * 64 + cb * 16) ^ swz;
            short8 a = *reinterpret_cast<const short8*>(buf + byte);
            acc0 = __builtin_amdgcn_mfma_f32_16x16x32_bf16(a, bfr0[ks], acc0, 0, 0, 0);
            acc1 = __builtin_amdgcn_mfma_f32_16x16x32_bf16(a, bfr1[ks], acc1, 0, 0, 0);
        }
        // C layout: col = lane&15, row = (lane>>4)*4 + r
        #pragma unroll
        for (int r = 0; r < 4; ++r) {
            pre[w][(lane >> 4) * 4 + r][(lane & 15)]      = acc0[r];
            pre[w][(lane >> 4) * 4 + r][16 + (lane & 15)] = acc1[r];
        }
        __syncthreads();                     // barrier 1: pre[] complete

        // ---- elementwise LSTM cell; c-state in regs ----
        float hp[2];
        #pragma unroll
        for (int e = 0; e < 2; ++e) {
            int col = epr * 2 + e;
            float ag = pre[0][erow][col] + bge[e];
            float ai = pre[1][erow][col] + bie[e];
            float af = pre[2][erow][col] + bfe[e];
            float ao = pre[3][erow][col] + boe[e];
            float g = tanhf_(ag), ii = sigf(ai), f = sigf(af), o = sigf(ao);
            float c = g * ii + cst[e] * f;
            cst[e] = c;
            hp[e] = tanhf_(c) * o;
        }
        uint32_t packed = (uint32_t)f2bf(hp[0]) | ((uint32_t)f2bf(hp[1]) << 16);
        uint32_t* hdst = reinterpret_cast<uint32_t*>(
            hbuf + (size_t)((t + 1) & 1) * B_ * H_ + (size_t)(b0 + erow) * H_ + hcg0);
        __hip_atomic_store(hdst, packed, __ATOMIC_RELAXED, __HIP_MEMORY_SCOPE_AGENT);
        // drain own h stores to the device coherence point, then signal
        asm volatile("s_waitcnt vmcnt(0)" ::: "memory");
        __syncthreads();                     // barrier 2: all stores drained
        if (tid == 0)
            __hip_atomic_store(myflag, t + 1, __ATOMIC_RELAXED, __HIP_MEMORY_SCOPE_AGENT);
    }
}

// ---- final projection: out[b][c] = h_T[b] . wph[:,c] + bp[c] ----
__global__ void k_proj(const uint16_t* __restrict__ hb0, const float* __restrict__ wph,
                       const float* __restrict__ bp, float* __restrict__ out) {
    int b = blockIdx.x, lane = threadIdx.x;     // 64 threads
    const uint32_t* hrow = reinterpret_cast<const uint32_t*>(hb0 + (size_t)b * H_);
    float p[C_];
    #pragma unroll
    for (int c = 0; c < C_; ++c) p[c] = 0.f;
    #pragma unroll
    for (int q = 0; q < 4; ++q) {
        int k2 = lane + q * 64;
        uint32_t u = __hip_atomic_load(hrow + k2, __ATOMIC_RELAXED, __HIP_MEMORY_SCOPE_AGENT);
        float h0 = bf2f((uint16_t)(u & 0xFFFFu));
        float h1 = bf2f((uint16_t)(u >> 16));
        #pragma unroll
        for (int c = 0; c < C_; ++c)
            p[c] += h0 * wph[(size_t)(2 * k2) * C_ + c] + h1 * wph[(size_t)(2 * k2 + 1) * C_ + c];
    }
    #pragma unroll
    for (int c = 0; c < C_; ++c) {
        float v = p[c];
        #pragma unroll
        for (int off = 32; off; off >>= 1) v += __shfl_down(v, off, 64);
        if (lane == 0) out[(size_t)b * C_ + c] = v + bp[c];
    }
}

extern "C" void kernel_launch(void* const* d_in, const int* in_sizes, int n_in,
                              void* d_out, int out_size, void* d_ws, size_t ws_size,
                              hipStream_t stream) {
    const float* x   = (const float*)d_in[0];
    const float* wgx = (const float*)d_in[1];
    const float* wgh = (const float*)d_in[2];
    const float* bg  = (const float*)d_in[3];
    const float* wix = (const float*)d_in[4];
    const float* wih = (const float*)d_in[5];
    const float* bi  = (const float*)d_in[6];
    const float* wfx = (const float*)d_in[7];
    const float* wfh = (const float*)d_in[8];
    const float* bf  = (const float*)d_in[9];
    const float* wox = (const float*)d_in[10];
    const float* woh = (const float*)d_in[11];
    const float* bo  = (const float*)d_in[12];
    const float* wph = (const float*)d_in[13];
    const float* bp  = (const float*)d_in[14];

    if (ws_size < WS_NEED) return;  // fail loud (wrong output) rather than corrupt

    char* ws = (char*)d_ws;
    uint16_t* xbp = (uint16_t*)(ws + OFF_XB);
    uint16_t* wcp = (uint16_t*)(ws + OFF_WC);
    uint16_t* hbp = (uint16_t*)(ws + OFF_HB);
    int*      flp = (int*)(ws + OFF_FL);

    hipMemsetAsync(flp, 0, SZ_FL, stream);
    k_cvt_x<<<(B_ * T_ * D_) / (256 * 4), 256, 0, stream>>>(x, xbp);
    k_build_w<<<4 * H_, 256, 0, stream>>>(wgh, wih, wfh, woh, wgx, wix, wfx, wox, wcp);
    k_lstm<<<256, 256, 0, stream>>>(xbp, wcp, bg, bi, bf, bo, hbp, flp);
    k_proj<<<B_, 64, 0, stream>>>(hbp /* parity 0 holds h_T */, wph, bp, (float*)d_out);
}

// Round 10
// 1444.833 us; speedup vs baseline: 1.1032x; 1.1032x over previous
//
#include <hip/hip_runtime.h>
#include <hip/hip_bf16.h>
#include <stdint.h>

typedef __attribute__((ext_vector_type(8))) short short8;
typedef __attribute__((ext_vector_type(4))) float floatx4;
typedef __attribute__((ext_vector_type(4))) unsigned int uintx4;
typedef __attribute__((ext_vector_type(4))) unsigned short ushort4v;

#define DEVI __device__ __forceinline__

// ---- problem sizes ----
constexpr int B_ = 256, T_ = 512, D_ = 128, H_ = 512, C_ = 10;
constexpr int KTOT = H_ + D_;       // 640: k = [h(512) ; x(128)]
constexpr int RG = 16;              // batch rows per group
constexpr int NBG = 16;             // batch groups
constexpr int NCG = 16;             // column groups
constexpr int HCW = 32;             // h-cols per WG

// ---- workspace layout (bytes) ----
constexpr size_t OFF_XB = 0;
constexpr size_t SZ_XB  = (size_t)B_ * T_ * D_ * 2;          // x in bf16
constexpr size_t OFF_WC = OFF_XB + SZ_XB;
constexpr size_t SZ_WC  = (size_t)4 * H_ * KTOT * 2;         // Wcomb[4*H][640] bf16
constexpr size_t OFF_HB = OFF_WC + SZ_WC;
constexpr size_t SZ_HB  = (size_t)2 * B_ * H_ * 2;           // h double buffer bf16
constexpr size_t OFF_FL = OFF_HB + SZ_HB;
constexpr size_t SZ_FL  = (size_t)NBG * NCG * 64;            // flags: 64B apart
constexpr size_t WS_NEED = OFF_FL + SZ_FL;

DEVI uint16_t f2bf(float f) {
    uint32_t u = __builtin_bit_cast(uint32_t, f);
    u += 0x7FFFu + ((u >> 16) & 1u);
    return (uint16_t)(u >> 16);
}
DEVI float bf2f(uint16_t u) {
    return __builtin_bit_cast(float, (uint32_t)u << 16);
}
DEVI float sigf(float x)  { return 1.0f / (1.0f + __expf(-x)); }
DEVI float tanhf_(float x){ return 1.0f - 2.0f / (1.0f + __expf(2.0f * x)); }

// ---- prep: x fp32 -> bf16 ----
__global__ void k_cvt_x(const float* __restrict__ x, uint16_t* __restrict__ xb) {
    int i = (blockIdx.x * 256 + threadIdx.x) * 4;
    float4 v = *reinterpret_cast<const float4*>(x + i);
    ushort4v o;
    o.x = f2bf(v.x); o.y = f2bf(v.y); o.z = f2bf(v.z); o.w = f2bf(v.w);
    *reinterpret_cast<ushort4v*>(xb + i) = o;
}

// ---- prep: build combined transposed bf16 weights Wcomb[n'=g*512+n][k] ----
__global__ void k_build_w(const float* __restrict__ wgh, const float* __restrict__ wih,
                          const float* __restrict__ wfh, const float* __restrict__ woh,
                          const float* __restrict__ wgx, const float* __restrict__ wix,
                          const float* __restrict__ wfx, const float* __restrict__ wox,
                          uint16_t* __restrict__ wc) {
    int np = blockIdx.x;            // 0..2047
    int g = np >> 9, n = np & 511;
    const float* wh = (g == 0) ? wgh : (g == 1) ? wih : (g == 2) ? wfh : woh;
    const float* wx = (g == 0) ? wgx : (g == 1) ? wix : (g == 2) ? wfx : wox;
    for (int k = threadIdx.x; k < KTOT; k += 256) {
        float v = (k < H_) ? wh[(size_t)k * H_ + n] : wx[(size_t)(k - H_) * H_ + n];
        wc[(size_t)np * KTOT + k] = f2bf(v);
    }
}

// Opaque 16B weight load (kept resident in the unified VGPR/AGPR file)
#define WLOAD(dst, base, IMM) \
    asm volatile("global_load_dwordx4 %0, %1, off offset:" #IMM \
                 : "=v"(dst) : "v"(base))
#define WLOAD20(arr, base) \
    WLOAD(arr[0],  base, 0);    WLOAD(arr[1],  base, 64);   \
    WLOAD(arr[2],  base, 128);  WLOAD(arr[3],  base, 192);  \
    WLOAD(arr[4],  base, 256);  WLOAD(arr[5],  base, 320);  \
    WLOAD(arr[6],  base, 384);  WLOAD(arr[7],  base, 448);  \
    WLOAD(arr[8],  base, 512);  WLOAD(arr[9],  base, 576);  \
    WLOAD(arr[10], base, 640);  WLOAD(arr[11], base, 704);  \
    WLOAD(arr[12], base, 768);  WLOAD(arr[13], base, 832);  \
    WLOAD(arr[14], base, 896);  WLOAD(arr[15], base, 960);  \
    WLOAD(arr[16], base, 1024); WLOAD(arr[17], base, 1088); \
    WLOAD(arr[18], base, 1152); WLOAD(arr[19], base, 1216)

// device-coherent 16B load (h exchange)
#define HLOAD(dst, base, IMM) \
    asm volatile("global_load_dwordx4 %0, %1, off offset:" #IMM " sc0 sc1" \
                 : "=v"(dst) : "v"(base) : "memory")

// ---- main recurrent kernel ----
// WG = 16 batch rows x 32 h-cols, 4 waves. Wave w owns cols w*8..w*8+7 for
// ALL FOUR gates: B-tile0 = [g cols | i cols], B-tile1 = [f | o]. The cell is
// computed fully in-wave (shfl_xor(8) gate exchange, shfl_xor(1) col pairing
// for coalesced u32 h-stores) -- no pre[] LDS roundtrip, no pre barrier.
// Sync per step (validated round-2/8 semantics, all device-scope):
//   producer: h store (sc1, relaxed) -> vmcnt(0) drain -> barrier -> tid0 flag
//   consumer: EVERY wave polls the 16 per-cg flags (lanes 0-15 + ballot)
__global__ __launch_bounds__(256, 1) void k_lstm(
    const uint16_t* __restrict__ xb,   // [B][T][D] bf16
    const uint16_t* __restrict__ wc,   // [4H][KTOT] bf16
    const float* __restrict__ bgp, const float* __restrict__ bip,
    const float* __restrict__ bfp, const float* __restrict__ bop,
    uint16_t* hbuf,                    // [2][B][H] bf16
    int* flags)                        // [NBG][NCG] ints, 64B apart
{
    __shared__ __align__(16) char hx[RG * KTOT * 2];              // 20 KB, XOR-swizzled

    const int tid  = threadIdx.x;
    const int lane = tid & 63;
    const int w    = tid >> 6;          // wave id -> col block w*8
    const int bid  = blockIdx.x;
    // keep each batch-group's 16 WGs on one XCD (perf heuristic only)
    const int xcd = bid & 7, j = bid >> 3;
    const int bg = xcd * 2 + (j >> 4);
    const int cg = j & 15;
    const int b0  = bg * RG;
    const int hc0 = cg * HCW;

    // ---- load this wave's weight slice into registers (resident all run) ----
    // B-frag: col = lane&15 -> tile col; k = (lane>>4)*8 + j
    // tile0 col c: c<8 -> gate g col (hc0+w*8+c); c>=8 -> gate i col (c-8)
    // tile1: gates f / o same split.  (validated round 3-5)
    short8 bfr0[20], bfr1[20];
    {
        const int lcol = lane & 15, kgrp = lane >> 4;
        const int cw = lcol & 7, hi2 = lcol >> 3;
        const int colg = hc0 + w * 8 + cw;
        const uint16_t* src0 = wc + (size_t)((0 + hi2) * H_ + colg) * KTOT + kgrp * 8;
        const uint16_t* src1 = wc + (size_t)((2 + hi2) * H_ + colg) * KTOT + kgrp * 8;
        WLOAD20(bfr0, src0);
        WLOAD20(bfr1, src1);
        asm volatile("s_waitcnt vmcnt(0)" ::: "memory");
    }

    // per-lane cell mapping: col = hc0+w*8+cl; lo lanes rows q*4+{0,1}, hi q*4+{2,3}
    const int cl   = lane & 7;
    const bool lo  = (lane & 8) == 0;
    const int rb   = (lane >> 4) * 4 + (lo ? 0 : 2);
    const int mycol = hc0 + w * 8 + cl;
    const float bgv = bgp[mycol], biv = bip[mycol], bfv = bfp[mycol], bov = bop[mycol];
    float cst[2] = {0.f, 0.f};

    // staging mapping: thread -> (row, 64B segment)
    const int srow = tid >> 4, sseg = tid & 15;
    const int sswz = (srow & 7) << 4;
    // A-fragment base (mfma 16x16x32: row = lane&15, k = (lane>>4)*8 + j)
    const int arow = lane & 15, akg = lane >> 4;
    const int abase = arow * (KTOT * 2) + akg * 16;
    const int aswz  = (arow & 7) << 4;

    int* fbase = flags + bg * NCG * 16;
    int* myflag = fbase + cg * 16;
    char* lds = hx;

    for (int t = 0; t < T_; ++t) {
        // ---- stage x part (cols 512..639): no h dependence; hx readers of
        //      step t-1 all passed the drain barrier ----
        {
            const short8 xv = *reinterpret_cast<const short8*>(
                xb + ((size_t)(b0 + srow) * T_ + t) * D_ + sseg * 8);
            int byte = srow * (KTOT * 2) + H_ * 2 + sseg * 16;
            *reinterpret_cast<short8*>(lds + (byte ^ sswz)) = xv;
        }

        if (t == 0) {
            uintx4 z = {0u, 0u, 0u, 0u};
            #pragma unroll
            for (int c4 = 0; c4 < 4; ++c4) {
                int byte = srow * (KTOT * 2) + sseg * 64 + c4 * 16;
                *reinterpret_cast<uintx4*>(lds + (byte ^ sswz)) = z;
            }
        } else {
            // ---- EVERY wave polls the 16 producer flags (lanes 0-15) ----
            {
                int it = 0;
                for (;;) {
                    int f = t;
                    if (lane < NCG)
                        f = __hip_atomic_load(fbase + lane * 16, __ATOMIC_RELAXED,
                                              __HIP_MEMORY_SCOPE_AGENT);
                    if (__ballot(f >= t) == ~0ull) break;
                    if (++it > (1 << 22)) break;   // fail loud, not hang
                }
                asm volatile("" ::: "memory");     // no reordering across detect
            }
            // ---- bulk h load: this thread's 64B chunk of [16 rows x 512 cols] ----
            const uint32_t* src = reinterpret_cast<const uint32_t*>(
                hbuf + (size_t)(t & 1) * B_ * H_ + (size_t)(b0 + srow) * H_ + sseg * 32);
            uintx4 v0, v1, v2, v3;
            HLOAD(v0, src, 0);  HLOAD(v1, src, 16);
            HLOAD(v2, src, 32); HLOAD(v3, src, 48);
            asm volatile("s_waitcnt vmcnt(0)" ::: "memory");
            #pragma unroll
            for (int c4 = 0; c4 < 4; ++c4) {
                uintx4 v = (c4 == 0) ? v0 : (c4 == 1) ? v1 : (c4 == 2) ? v2 : v3;
                int byte = srow * (KTOT * 2) + sseg * 64 + c4 * 16;
                *reinterpret_cast<uintx4*>(lds + (byte ^ sswz)) = v;
            }
        }
        __syncthreads();                 // barrier A: staging complete

        // ---- MFMA: [16 rows x 16 cols] x 2 tiles, K = 640 ----
        floatx4 acc0 = {0.f, 0.f, 0.f, 0.f}, acc1 = {0.f, 0.f, 0.f, 0.f};
        #pragma unroll
        for (int ks = 0; ks < 20; ++ks) {
            int byte = (abase + ks * 64) ^ aswz;
            short8 a = *reinterpret_cast<const short8*>(lds + byte);
            acc0 = __builtin_amdgcn_mfma_f32_16x16x32_bf16(a, bfr0[ks], acc0, 0, 0, 0);
            acc1 = __builtin_amdgcn_mfma_f32_16x16x32_bf16(a, bfr1[ks], acc1, 0, 0, 0);
        }

        // ---- in-wave gate exchange + cell (C layout: col=lane&15, row=(lane>>4)*4+r) ----
        float q0[4], q1[4];
        #pragma unroll
        for (int r = 0; r < 4; ++r) {
            q0[r] = __shfl_xor(acc0[r], 8, 64);
            q1[r] = __shfl_xor(acc1[r], 8, 64);
        }
        float hpair[2];
        #pragma unroll
        for (int e = 0; e < 2; ++e) {
            // lo lane: rows rb+e use C-rows e; hi lane: C-rows 2+e (static)
            float pg = lo ? acc0[e] : q0[2 + e];
            float pi = lo ? q0[e]   : acc0[2 + e];
            float pf = lo ? acc1[e] : q1[2 + e];
            float po = lo ? q1[e]   : acc1[2 + e];
            float g = tanhf_(pg + bgv), ii = sigf(pi + biv);
            float f = sigf(pf + bfv),   o  = sigf(po + bov);
            float c = g * ii + cst[e] * f;
            cst[e] = c;
            hpair[e] = tanhf_(c) * o;
        }
        // pair adjacent cols into one u32 via shfl_xor(1):
        //   even cl stores row rb   : (my col cl, partner col cl+1)
        //   odd  cl stores row rb+1 : (partner col cl-1, my col cl)
        float p0 = __shfl_xor(hpair[0], 1, 64);
        float p1 = __shfl_xor(hpair[1], 1, 64);
        uint32_t word; int strow;
        if ((cl & 1) == 0) {
            word = (uint32_t)f2bf(hpair[0]) | ((uint32_t)f2bf(p0) << 16);
            strow = rb;
        } else {
            word = (uint32_t)f2bf(p1) | ((uint32_t)f2bf(hpair[1]) << 16);
            strow = rb + 1;
        }
        uint32_t* hdst = reinterpret_cast<uint32_t*>(
            hbuf + (size_t)((t + 1) & 1) * B_ * H_
                 + (size_t)(b0 + strow) * H_ + hc0 + w * 8 + (cl & ~1));
        __hip_atomic_store(hdst, word, __ATOMIC_RELAXED, __HIP_MEMORY_SCOPE_AGENT);
        // drain own h stores to the device coherence point, then signal
        asm volatile("s_waitcnt vmcnt(0)" ::: "memory");
        __syncthreads();                 // barrier B: all stores drained
        if (tid == 0)
            __hip_atomic_store(myflag, t + 1, __ATOMIC_RELAXED, __HIP_MEMORY_SCOPE_AGENT);
    }
}

// ---- final projection: out[b][c] = h_T[b] . wph[:,c] + bp[c] ----
__global__ void k_proj(const uint16_t* __restrict__ hb0, const float* __restrict__ wph,
                       const float* __restrict__ bp, float* __restrict__ out) {
    int b = blockIdx.x, lane = threadIdx.x;     // 64 threads
    const uint32_t* hrow = reinterpret_cast<const uint32_t*>(hb0 + (size_t)b * H_);
    float p[C_];
    #pragma unroll
    for (int c = 0; c < C_; ++c) p[c] = 0.f;
    #pragma unroll
    for (int q = 0; q < 4; ++q) {
        int k2 = lane + q * 64;
        uint32_t u = __hip_atomic_load(hrow + k2, __ATOMIC_RELAXED, __HIP_MEMORY_SCOPE_AGENT);
        float h0 = bf2f((uint16_t)(u & 0xFFFFu));
        float h1 = bf2f((uint16_t)(u >> 16));
        #pragma unroll
        for (int c = 0; c < C_; ++c)
            p[c] += h0 * wph[(size_t)(2 * k2) * C_ + c] + h1 * wph[(size_t)(2 * k2 + 1) * C_ + c];
    }
    #pragma unroll
    for (int c = 0; c < C_; ++c) {
        float v = p[c];
        #pragma unroll
        for (int off = 32; off; off >>= 1) v += __shfl_down(v, off, 64);
        if (lane == 0) out[(size_t)b * C_ + c] = v + bp[c];
    }
}

extern "C" void kernel_launch(void* const* d_in, const int* in_sizes, int n_in,
                              void* d_out, int out_size, void* d_ws, size_t ws_size,
                              hipStream_t stream) {
    const float* x   = (const float*)d_in[0];
    const float* wgx = (const float*)d_in[1];
    const float* wgh = (const float*)d_in[2];
    const float* bg  = (const float*)d_in[3];
    const float* wix = (const float*)d_in[4];
    const float* wih = (const float*)d_in[5];
    const float* bi  = (const float*)d_in[6];
    const float* wfx = (const float*)d_in[7];
    const float* wfh = (const float*)d_in[8];
    const float* bf  = (const float*)d_in[9];
    const float* wox = (const float*)d_in[10];
    const float* woh = (const float*)d_in[11];
    const float* bo  = (const float*)d_in[12];
    const float* wph = (const float*)d_in[13];
    const float* bp  = (const float*)d_in[14];

    if (ws_size < WS_NEED) return;  // fail loud (wrong output) rather than corrupt

    char* ws = (char*)d_ws;
    uint16_t* xbp = (uint16_t*)(ws + OFF_XB);
    uint16_t* wcp = (uint16_t*)(ws + OFF_WC);
    uint16_t* hbp = (uint16_t*)(ws + OFF_HB);
    int*      flp = (int*)(ws + OFF_FL);

    hipMemsetAsync(flp, 0, SZ_FL, stream);
    k_cvt_x<<<(B_ * T_ * D_) / (256 * 4), 256, 0, stream>>>(x, xbp);
    k_build_w<<<4 * H_, 256, 0, stream>>>(wgh, wih, wfh, woh, wgx, wix, wfx, wox, wcp);
    k_lstm<<<256, 256, 0, stream>>>(xbp, wcp, bg, bi, bf, bo, hbp, flp);
    k_proj<<<B_, 64, 0, stream>>>(hbp /* parity 0 holds h_T */, wph, bp, (float*)d_out);
}